// Round 2
// baseline (10602.435 us; speedup 1.0000x reference)
//
#include <hip/hip_runtime.h>
#include <math.h>

#define T_LEN 2048
#define B_SZ  16
#define GN_NP 128

// ======================= conv as implicit GEMM (fp32) =======================
// in:  [bc][Cin][T], wp: [Cin*K][Cout] (pre-transformed), out: [bc][Cout][T]
// tile: 64 t  x  (16*OPT) o per block, 256 threads, each thread 4t x OPT o.
template<int OPT, int K>
__global__ __launch_bounds__(256, 2) void conv_gemm(
    const float* __restrict__ in, const float* __restrict__ wp,
    const float* __restrict__ bias, float* __restrict__ out,
    int Cin, int Cout, int PAD)
{
  const int T  = T_LEN;
  const int TT = 64;
  const int TO = 16 * OPT;
  const int ICOLS = TT + K - 1;
  __shared__ float s_in[8][TT + 8];
  __shared__ float s_w[8 * K][TO];
  const int tid = threadIdx.x;
  const int tx  = tid & 15;
  const int ty  = tid >> 4;
  const int t0  = blockIdx.x * TT;
  const int o0  = blockIdx.y * TO;
  const int b   = blockIdx.z;
  float acc[4][OPT];
#pragma unroll
  for (int j = 0; j < 4; ++j)
#pragma unroll
    for (int r = 0; r < OPT; ++r) acc[j][r] = 0.f;
  const int CK = Cin * K;
  for (int ic0 = 0; ic0 < Cin; ic0 += 8) {
    for (int l = tid; l < 8 * ICOLS; l += 256) {
      int rr = l / ICOLS, cc = l % ICOLS;
      int ch = ic0 + rr;
      int t  = t0 + cc - PAD;
      float v = 0.f;
      if (ch < Cin && t >= 0 && t < T) v = in[((size_t)b * Cin + ch) * T + t];
      s_in[rr][cc] = v;
    }
    for (int l = tid; l < 8 * K * TO; l += 256) {
      int rr = l / TO, cc = l % TO;
      int g  = ic0 * K + rr;
      float v = 0.f;
      if (g < CK && (o0 + cc) < Cout) v = wp[(size_t)g * Cout + o0 + cc];
      s_w[rr][cc] = v;
    }
    __syncthreads();
#pragma unroll
    for (int ii = 0; ii < 8; ++ii) {
#pragma unroll
      for (int k = 0; k < K; ++k) {
        float av[4];
#pragma unroll
        for (int j = 0; j < 4; ++j) av[j] = s_in[ii][tx + 16 * j + k];
        const float* wrow = &s_w[ii * K + k][ty * OPT];
#pragma unroll
        for (int r = 0; r < OPT; ++r) {
          float wv = wrow[r];
#pragma unroll
          for (int j = 0; j < 4; ++j) acc[j][r] = fmaf(av[j], wv, acc[j][r]);
        }
      }
    }
    __syncthreads();
  }
#pragma unroll
  for (int r = 0; r < OPT; ++r) {
    int o = o0 + ty * OPT + r;
    if (o < Cout) {
      float bv = bias ? bias[o] : 0.f;
#pragma unroll
      for (int j = 0; j < 4; ++j) {
        int t = t0 + tx + 16 * j;
        out[((size_t)b * Cout + o) * T + t] = acc[j][r] + bv;
      }
    }
  }
}

// ======================= small helper kernels =======================

// normalize codebook rows (512) and speaker rows (64), dim 128
__global__ void norm_rows_k(const float* __restrict__ cb, const float* __restrict__ spk,
                            float* __restrict__ cbn, float* __restrict__ sn) {
  int r = blockIdx.x;
  int c = threadIdx.x;   // 128 threads
  const float* src;
  float* dst;
  if (r < 512) { src = cb + (size_t)r * 128;          dst = cbn + (size_t)r * 128; }
  else         { src = spk + (size_t)(r - 512) * 128; dst = sn + (size_t)(r - 512) * 128; }
  float v = src[c];
  float p = v * v;
  for (int off = 32; off; off >>= 1) p += __shfl_down(p, off);
  __shared__ float ls[2];
  if ((c & 63) == 0) ls[c >> 6] = p;
  __syncthreads();
  float ss = ls[0] + ls[1];
  dst[c] = v * (1.f / sqrtf(ss + 1e-12f));
}

// yv[b][c][t] = sn[y[b][t]][c]   (full batch of 16)
__global__ void yv_fill_k(const int* __restrict__ y, const float* __restrict__ sn,
                          float* __restrict__ yv) {
  const int T = T_LEN;
  size_t idx = (size_t)blockIdx.x * 256 + threadIdx.x;
  size_t total = (size_t)B_SZ * 128 * T;
  if (idx >= total) return;
  int t = idx & (T - 1);
  int c = (idx / T) & 127;
  int b = idx / ((size_t)128 * T);
  int yb = y[(size_t)b * T + t];
  yv[idx] = sn[(size_t)yb * 128 + c];
}

// weight prep: encoder Conv1d  w[O][I][K] -> wp[(i*K+k)*Cout + o]
__global__ void prep_w_enc_k(const float* __restrict__ w, float* __restrict__ wp,
                             int Cin, int Cout, int K) {
  size_t idx = (size_t)blockIdx.x * 256 + threadIdx.x;
  size_t total = (size_t)Cin * K * Cout;
  if (idx >= total) return;
  int g = idx / Cout, o = idx % Cout;
  wp[idx] = w[(size_t)o * Cin * K + g];
}

// weight prep: ConvTranspose1d  w[I][O][K]; wT[o,i,k]=w[i,o,K-1-k] -> wp[(i*K+k)*Cout+o]
__global__ void prep_w_dec_k(const float* __restrict__ w, float* __restrict__ wp,
                             int Cin, int Cout, int K) {
  size_t idx = (size_t)blockIdx.x * 256 + threadIdx.x;
  size_t total = (size_t)Cin * K * Cout;
  if (idx >= total) return;
  int g = idx / Cout, o = idx % Cout;
  int i = g / K, k = g % K;
  wp[idx] = w[((size_t)i * Cout + o) * K + (K - 1 - k)];
}

// codebook^T prep for VQ GEMM: wp[c*512 + k] = cbn[k*128 + c]
__global__ void prep_cbt_k(const float* __restrict__ cbn, float* __restrict__ wp) {
  size_t idx = (size_t)blockIdx.x * 256 + threadIdx.x;
  if (idx >= (size_t)128 * 512) return;
  int c = idx / 512, k = idx % 512;
  wp[idx] = cbn[(size_t)k * 128 + c];
}

// GroupNorm(1,C) deterministic partials: grid (GN_NP, bc)
__global__ __launch_bounds__(256) void gn_stats_k(const float* __restrict__ x,
                                                  float* __restrict__ part, int C) {
  const int T = T_LEN;
  int b = blockIdx.y;
  size_t total = (size_t)C * T;
  size_t per = total / GN_NP;
  const float* base = x + (size_t)b * total + (size_t)blockIdx.x * per;
  float s = 0.f, ss = 0.f;
  for (size_t i = threadIdx.x; i < per; i += 256) {
    float v = base[i];
    s += v; ss += v * v;
  }
  for (int off = 32; off; off >>= 1) { s += __shfl_down(s, off); ss += __shfl_down(ss, off); }
  __shared__ float l1[4], l2[4];
  int w = threadIdx.x >> 6;
  if ((threadIdx.x & 63) == 0) { l1[w] = s; l2[w] = ss; }
  __syncthreads();
  if (threadIdx.x == 0) {
    part[((size_t)b * GN_NP + blockIdx.x) * 2]     = l1[0] + l1[1] + l1[2] + l1[3];
    part[((size_t)b * GN_NP + blockIdx.x) * 2 + 1] = l2[0] + l2[1] + l2[2] + l2[3];
  }
}

// finalize: grid (bc), 128 threads
__global__ void gn_finalize_k(const float* __restrict__ part, float* __restrict__ stats,
                              float invN) {
  int b = blockIdx.x;
  int p = threadIdx.x;
  float s  = part[((size_t)b * GN_NP + p) * 2];
  float ss = part[((size_t)b * GN_NP + p) * 2 + 1];
  for (int off = 32; off; off >>= 1) { s += __shfl_down(s, off); ss += __shfl_down(ss, off); }
  __shared__ float l1[2], l2[2];
  if ((p & 63) == 0) { l1[p >> 6] = s; l2[p >> 6] = ss; }
  __syncthreads();
  if (p == 0) {
    float S = l1[0] + l1[1], SS = l2[0] + l2[1];
    float m = S * invN;
    float var = fmaxf(SS * invN - m * m, 0.f);
    stats[b * 2]     = m;
    stats[b * 2 + 1] = 1.f / sqrtf(var + 1e-5f);
  }
}

// in-place GN + LeakyReLU; grid (T/256, C, bc)
__global__ void gn_lrelu_k(float* __restrict__ x, const float* __restrict__ g,
                           const float* __restrict__ bt, const float* __restrict__ stats,
                           int C) {
  const int T = T_LEN;
  int b = blockIdx.z, c = blockIdx.y;
  int t = blockIdx.x * 256 + threadIdx.x;
  float m = stats[b * 2], rs = stats[b * 2 + 1];
  size_t i = ((size_t)b * C + c) * T + t;
  float v = (x[i] - m) * rs * g[c] + bt[c];
  x[i] = v >= 0.f ? v : 0.02f * v;
}

// GN + GLU: x [bc][1024][T] -> out [bc][512][T]; grid (T/256, 512, bc)
__global__ void gn_glu_k(const float* __restrict__ x, float* __restrict__ out,
                         const float* __restrict__ g, const float* __restrict__ bt,
                         const float* __restrict__ stats) {
  const int T = T_LEN, C = 1024, Co = 512;
  int b = blockIdx.z, c = blockIdx.y;
  int t = blockIdx.x * 256 + threadIdx.x;
  float m = stats[b * 2], rs = stats[b * 2 + 1];
  float a  = (x[((size_t)b * C + c) * T + t]      - m) * rs * g[c]      + bt[c];
  float gt = (x[((size_t)b * C + Co + c) * T + t] - m) * rs * g[Co + c] + bt[Co + c];
  out[((size_t)b * Co + c) * T + t] = a * (1.f / (1.f + expf(-gt)));
}

// argmax over 512 codes; sims [bc][512][T]; first-index tie-break (strict >)
__global__ void argmax_k(const float* __restrict__ sims, int* __restrict__ idx) {
  const int T = T_LEN;
  int b = blockIdx.y;
  int t = blockIdx.x * 256 + threadIdx.x;
  float best = -3.4e38f;
  int bi = 0;
  for (int k = 0; k < 512; ++k) {
    float v = sims[((size_t)b * 512 + k) * T + t];
    if (v > best) { best = v; bi = k; }
  }
  idx[(size_t)b * T + t] = bi;
}

// out [bc][256][T]: c<128 -> cbn[idx[b][t]][c], else yv[b][c-128][t]
__global__ void zqcat_k(const int* __restrict__ idx, const float* __restrict__ cbn,
                        const float* __restrict__ yv, float* __restrict__ out, int nb) {
  const int T = T_LEN;
  size_t i = (size_t)blockIdx.x * 256 + threadIdx.x;
  size_t total = (size_t)nb * 256 * T;
  if (i >= total) return;
  int t = i & (T - 1);
  int c = (i / T) & 255;
  int b = i / ((size_t)256 * T);
  float v;
  if (c < 128) {
    int ki = idx[(size_t)b * T + t];
    v = cbn[(size_t)ki * 128 + c];
  } else {
    v = yv[((size_t)b * 128 + (c - 128)) * T + t];
  }
  out[i] = v;
}

// out [bc][Ca+128][T] = concat(a [bc][Ca][T], yv [bc][128][T])
__global__ void cat_yv_k(const float* __restrict__ a, const float* __restrict__ yv,
                         float* __restrict__ out, int Ca, int nb) {
  const int T = T_LEN;
  int Ct = Ca + 128;
  size_t i = (size_t)blockIdx.x * 256 + threadIdx.x;
  size_t total = (size_t)nb * Ct * T;
  if (i >= total) return;
  int t = i & (T - 1);
  int c = (int)((i / T) % Ct);
  int b = (int)(i / ((size_t)Ct * T));
  float v;
  if (c < Ca) v = a[((size_t)b * Ca + c) * T + t];
  else        v = yv[((size_t)b * 128 + (c - Ca)) * T + t];
  out[i] = v;
}

// ======================= host side =======================

extern "C" void kernel_launch(void* const* d_in, const int* in_sizes, int n_in,
                              void* d_out, int out_size, void* d_ws, size_t ws_size,
                              hipStream_t stream) {
  const int T = T_LEN;
  const float* x    = (const float*)d_in[0];
  const int*   y    = (const int*)d_in[1];
  const float* spk  = (const float*)d_in[2];
  const float* cb   = (const float*)d_in[3];
  const float* ew0  = (const float*)d_in[4];
  const float* eb0  = (const float*)d_in[5];
  const float* eg0  = (const float*)d_in[6];
  const float* et0  = (const float*)d_in[7];
  const float* ew1  = (const float*)d_in[8];
  const float* eb1  = (const float*)d_in[9];
  const float* eg1  = (const float*)d_in[10];
  const float* et1  = (const float*)d_in[11];
  const float* ew2  = (const float*)d_in[12];
  const float* eb2  = (const float*)d_in[13];
  const float* eg2  = (const float*)d_in[14];
  const float* et2  = (const float*)d_in[15];
  const float* mw   = (const float*)d_in[16];
  const float* mb   = (const float*)d_in[17];
  const float* dw0  = (const float*)d_in[18];
  const float* db0  = (const float*)d_in[19];
  const float* dg0  = (const float*)d_in[20];
  const float* dt0  = (const float*)d_in[21];
  const float* dw1  = (const float*)d_in[22];
  const float* db1  = (const float*)d_in[23];
  const float* dg1  = (const float*)d_in[24];
  const float* dt1  = (const float*)d_in[25];
  const float* dw2  = (const float*)d_in[26];
  const float* db2  = (const float*)d_in[27];
  float* out = (float*)d_out;
  (void)in_sizes; (void)n_in; (void)out_size;

  // ---- element counts ----
  const size_t SZ_CBN = 512 * 128, SZ_SN = 64 * 128, SZ_YV = (size_t)16 * 128 * T;
  const size_t SZ_IDX = 16 * T, SZ_PART = (size_t)16 * GN_NP * 2, SZ_STATS = 64;
  const size_t SZ_WE0 = (size_t)39 * 5 * 1024, SZ_WE1 = (size_t)1024 * 5 * 512;
  const size_t SZ_WE2 = (size_t)512 * 5 * 512, SZ_WM = (size_t)512 * 128;
  const size_t SZ_WCB = (size_t)128 * 512, SZ_WD0 = (size_t)256 * 5 * 1024;
  const size_t SZ_WD1 = (size_t)640 * 5 * 1024, SZ_WD2 = (size_t)640 * 5 * 39;

  auto al = [](size_t elems) { return ((elems * 4 + 255) & ~(size_t)255); };
  const size_t fixedB = al(SZ_CBN) + al(SZ_SN) + al(SZ_YV) + al(SZ_IDX) + al(SZ_PART) + al(SZ_STATS);
  const size_t wfullB = al(SZ_WE0) + al(SZ_WE1) + al(SZ_WE2) + al(SZ_WM) + al(SZ_WCB) +
                        al(SZ_WD0) + al(SZ_WD1) + al(SZ_WD2);
  const size_t wshB = al(SZ_WD1);  // largest single weight buffer
  auto chunkB = [&](int c) {
    return al((size_t)c * 1024 * T) + al((size_t)c * 640 * T) +
           al((size_t)c * 512 * T) + al((size_t)c * 128 * T);
  };

  int bc = 0;
  bool shw = false;
  {
    const int cands[5] = {16, 8, 4, 2, 1};
    for (int i = 0; i < 5 && !bc; ++i)
      if (fixedB + wfullB + chunkB(cands[i]) <= ws_size) bc = cands[i];
    if (!bc) {
      shw = true;
      for (int i = 0; i < 5 && !bc; ++i)
        if (fixedB + wshB + chunkB(cands[i]) <= ws_size) bc = cands[i];
    }
    if (!bc) return;  // cannot fit even minimal plan
  }

  // ---- pointer assignment ----
  char* base = (char*)d_ws;
  size_t off = 0;
  auto take = [&](size_t elems) -> float* {
    float* r = (float*)(base + off);
    off += al(elems);
    return r;
  };
  float* cbn   = take(SZ_CBN);
  float* sn    = take(SZ_SN);
  float* yv    = take(SZ_YV);
  int*   idx   = (int*)take(SZ_IDX);
  float* part  = take(SZ_PART);
  float* stats = take(SZ_STATS);
  float *w_e0, *w_e1, *w_e2, *w_m, *w_cb, *w_d0, *w_d1, *w_d2;
  if (!shw) {
    w_e0 = take(SZ_WE0); w_e1 = take(SZ_WE1); w_e2 = take(SZ_WE2); w_m = take(SZ_WM);
    w_cb = take(SZ_WCB); w_d0 = take(SZ_WD0); w_d1 = take(SZ_WD1); w_d2 = take(SZ_WD2);
  } else {
    float* wsh = take(SZ_WD1);
    w_e0 = w_e1 = w_e2 = w_m = w_cb = w_d0 = w_d1 = w_d2 = wsh;
  }
  float* A  = take((size_t)bc * 1024 * T);
  float* Bb = take((size_t)bc * 640 * T);
  float* C  = take((size_t)bc * 512 * T);
  float* z  = take((size_t)bc * 128 * T);

  dim3 blk(256);
  auto nblk = [](size_t total) { return dim3((unsigned)((total + 255) / 256)); };

  // ---- one-time prep ----
  norm_rows_k<<<576, 128, 0, stream>>>(cb, spk, cbn, sn);
  yv_fill_k<<<nblk((size_t)16 * 128 * T), blk, 0, stream>>>(y, sn, yv);
  if (!shw) {
    prep_w_enc_k<<<nblk(SZ_WE0), blk, 0, stream>>>(ew0, w_e0, 39, 1024, 5);
    prep_w_enc_k<<<nblk(SZ_WE1), blk, 0, stream>>>(ew1, w_e1, 1024, 512, 5);
    prep_w_enc_k<<<nblk(SZ_WE2), blk, 0, stream>>>(ew2, w_e2, 512, 512, 5);
    prep_w_enc_k<<<nblk(SZ_WM),  blk, 0, stream>>>(mw, w_m, 512, 128, 1);
    prep_cbt_k  <<<nblk(SZ_WCB), blk, 0, stream>>>(cbn, w_cb);
    prep_w_dec_k<<<nblk(SZ_WD0), blk, 0, stream>>>(dw0, w_d0, 256, 1024, 5);
    prep_w_dec_k<<<nblk(SZ_WD1), blk, 0, stream>>>(dw1, w_d1, 640, 1024, 5);
    prep_w_dec_k<<<nblk(SZ_WD2), blk, 0, stream>>>(dw2, w_d2, 640, 39, 5);
  }

  for (int b0 = 0; b0 < 16; b0 += bc) {
    const float* xin  = x   + (size_t)b0 * 39 * T;
    float*       yvc  = yv  + (size_t)b0 * 128 * T;
    int*         idxc = idx + (size_t)b0 * T;
    float*       outc = out + (size_t)b0 * 39 * T;

    // encoder layer 0: 39 -> 1024
    if (shw) prep_w_enc_k<<<nblk(SZ_WE0), blk, 0, stream>>>(ew0, w_e0, 39, 1024, 5);
    conv_gemm<8, 5><<<dim3(T / 64, 8, bc), blk, 0, stream>>>(xin, w_e0, eb0, A, 39, 1024, 2);
    gn_stats_k<<<dim3(GN_NP, bc), blk, 0, stream>>>(A, part, 1024);
    gn_finalize_k<<<bc, 128, 0, stream>>>(part, stats, 1.f / (1024.f * T));
    gn_lrelu_k<<<dim3(T / 256, 1024, bc), blk, 0, stream>>>(A, eg0, et0, stats, 1024);

    // encoder layer 1: 1024 -> 512
    if (shw) prep_w_enc_k<<<nblk(SZ_WE1), blk, 0, stream>>>(ew1, w_e1, 1024, 512, 5);
    conv_gemm<8, 5><<<dim3(T / 64, 4, bc), blk, 0, stream>>>(A, w_e1, eb1, C, 1024, 512, 2);
    gn_stats_k<<<dim3(GN_NP, bc), blk, 0, stream>>>(C, part, 512);
    gn_finalize_k<<<bc, 128, 0, stream>>>(part, stats, 1.f / (512.f * T));
    gn_lrelu_k<<<dim3(T / 256, 512, bc), blk, 0, stream>>>(C, eg1, et1, stats, 512);

    // encoder layer 2: 512 -> 512
    if (shw) prep_w_enc_k<<<nblk(SZ_WE2), blk, 0, stream>>>(ew2, w_e2, 512, 512, 5);
    conv_gemm<8, 5><<<dim3(T / 64, 4, bc), blk, 0, stream>>>(C, w_e2, eb2, Bb, 512, 512, 2);
    gn_stats_k<<<dim3(GN_NP, bc), blk, 0, stream>>>(Bb, part, 512);
    gn_finalize_k<<<bc, 128, 0, stream>>>(part, stats, 1.f / (512.f * T));
    gn_lrelu_k<<<dim3(T / 256, 512, bc), blk, 0, stream>>>(Bb, eg2, et2, stats, 512);

    // bottleneck 1x1: 512 -> 128 (z)
    if (shw) prep_w_enc_k<<<nblk(SZ_WM), blk, 0, stream>>>(mw, w_m, 512, 128, 1);
    conv_gemm<8, 1><<<dim3(T / 64, 1, bc), blk, 0, stream>>>(Bb, w_m, mb, z, 512, 128, 0);

    // VQ sims: z . cbn^T -> A (bc x 512 x T), then argmax
    if (shw) prep_cbt_k<<<nblk(SZ_WCB), blk, 0, stream>>>(cbn, w_cb);
    conv_gemm<8, 1><<<dim3(T / 64, 4, bc), blk, 0, stream>>>(z, w_cb, nullptr, A, 128, 512, 0);
    argmax_k<<<dim3(T / 256, bc), blk, 0, stream>>>(A, idxc);

    // concat(zq, yv) -> Bb [bc][256][T]
    zqcat_k<<<nblk((size_t)bc * 256 * T), blk, 0, stream>>>(idxc, cbn, yvc, Bb, bc);

    // decoder layer 0: 256 -> 1024, GN + GLU -> C [512]
    if (shw) prep_w_dec_k<<<nblk(SZ_WD0), blk, 0, stream>>>(dw0, w_d0, 256, 1024, 5);
    conv_gemm<8, 5><<<dim3(T / 64, 8, bc), blk, 0, stream>>>(Bb, w_d0, db0, A, 256, 1024, 2);
    gn_stats_k<<<dim3(GN_NP, bc), blk, 0, stream>>>(A, part, 1024);
    gn_finalize_k<<<bc, 128, 0, stream>>>(part, stats, 1.f / (1024.f * T));
    gn_glu_k<<<dim3(T / 256, 512, bc), blk, 0, stream>>>(A, C, dg0, dt0, stats);

    // concat(h, yv) -> Bb [bc][640][T]
    cat_yv_k<<<nblk((size_t)bc * 640 * T), blk, 0, stream>>>(C, yvc, Bb, 512, bc);

    // decoder layer 1: 640 -> 1024, GN + GLU -> C [512]
    if (shw) prep_w_dec_k<<<nblk(SZ_WD1), blk, 0, stream>>>(dw1, w_d1, 640, 1024, 5);
    conv_gemm<8, 5><<<dim3(T / 64, 8, bc), blk, 0, stream>>>(Bb, w_d1, db1, A, 640, 1024, 2);
    gn_stats_k<<<dim3(GN_NP, bc), blk, 0, stream>>>(A, part, 1024);
    gn_finalize_k<<<bc, 128, 0, stream>>>(part, stats, 1.f / (1024.f * T));
    gn_glu_k<<<dim3(T / 256, 512, bc), blk, 0, stream>>>(A, C, dg1, dt1, stats);

    // concat(h, yv) -> Bb [bc][640][T]
    cat_yv_k<<<nblk((size_t)bc * 640 * T), blk, 0, stream>>>(C, yvc, Bb, 512, bc);

    // decoder layer 2: 640 -> 39 -> out
    if (shw) prep_w_dec_k<<<nblk(SZ_WD2), blk, 0, stream>>>(dw2, w_d2, 640, 39, 5);
    conv_gemm<4, 5><<<dim3(T / 64, 1, bc), blk, 0, stream>>>(Bb, w_d2, db2, outc, 640, 39, 2);
  }
}

// Round 3
// 3909.752 us; speedup vs baseline: 2.7118x; 2.7118x over previous
//
#include <hip/hip_runtime.h>
#include <math.h>

#define T_LEN 2048
#define GN_NP 128

typedef _Float16 half_t;
typedef __attribute__((ext_vector_type(8))) _Float16 f16x8;
typedef __attribute__((ext_vector_type(4))) float f32x4;

// ===================== conv as implicit GEMM via MFMA =====================
// out[b][o][t] = bias[o] + sum_{tap,i} w[o][tap][i] * in[b][i][t + tap - PAD]
// A-operand: M = t (256/block), K = channels (32/step); B: N = o (64/block).
// SPLIT=1: inputs/weights are (hi, lo*4096) fp16 pairs; acc_lo rescaled at store.
// LDS rows are 64B (32ch fp16) with chunk-XOR swizzle c^=( (row>>1)&3 ) -> <=2-way conflicts.
template<int SPLIT, int KT>
__global__ __launch_bounds__(256, 2) void conv_mfma(
    const half_t* __restrict__ inH, const half_t* __restrict__ inL,
    const half_t* __restrict__ wH,  const half_t* __restrict__ wL,
    const float* __restrict__ bias, float* __restrict__ out,
    int Cin, int Cinp, int Cout)
{
  constexpr int T   = T_LEN;
  constexpr int BT  = 256;
  constexpr int PAD = (KT - 1) / 2;
  constexpr int RA  = BT + KT - 1;          // A rows (t window)
  constexpr int NP  = SPLIT ? 2 : 1;
  constexpr int ABYTES = RA * 64;
  constexpr int BBYTES = KT * 64 * 64;
  __shared__ __align__(16) char smem[(ABYTES + BBYTES) * NP];

  const int tid = threadIdx.x;
  const int t0  = blockIdx.x * BT;
  const int o0  = blockIdx.y * 64;
  const int b   = blockIdx.z;

  const int l  = tid & 63;
  const int wv = tid >> 6;      // wave id: t-quadrant
  const int lm = l & 15;
  const int g  = l >> 4;

  f32x4 acc[4][4] = {};
  f32x4 acc2[4][4] = {};

  const int g8  = tid & 7;      // 4-channel group for A staging
  const int rp0 = tid >> 3;     // row-pair id

  const int nib = Cinp >> 5;
  for (int ib = 0; ib < nib; ++ib) {
    // ---------------- stage A (transpose [ch][t] -> [t][ch]) ----------------
    #pragma unroll
    for (int p = 0; p < NP; ++p) {
      const half_t* src = p ? inL : inH;
      char* Ab = smem + p * ABYTES;
      for (int rp = rp0; rp < RA / 2; rp += 32) {
        const int r0 = rp * 2;
        ushort v0[4], v1[4];
        #pragma unroll
        for (int c = 0; c < 4; ++c) {
          const int ch = (ib << 5) + g8 * 4 + c;
          const int t  = t0 - PAD + r0;     // even -> pair never straddles bounds
          unsigned int dv = 0;
          if (ch < Cin && t >= 0 && t < T)
            dv = *(const unsigned int*)(src + ((size_t)b * Cin + ch) * T + t);
          v0[c] = (ushort)(dv & 0xffffu);
          v1[c] = (ushort)(dv >> 16);
        }
        const int cI = g8 >> 1, sI = g8 & 1;
        const int by0 = r0 * 64 + ((cI ^ ((r0 >> 1) & 3)) * 16) + sI * 8;
        const int by1 = (r0 + 1) * 64 + ((cI ^ (((r0 + 1) >> 1) & 3)) * 16) + sI * 8;
        *(ushort4*)(Ab + by0) = make_ushort4(v0[0], v0[1], v0[2], v0[3]);
        *(ushort4*)(Ab + by1) = make_ushort4(v1[0], v1[1], v1[2], v1[3]);
      }
    }
    // ---------------- stage B (weights [o][tap][i], 16B chunks) ----------------
    #pragma unroll
    for (int p = 0; p < NP; ++p) {
      const half_t* wsrc = p ? wL : wH;
      char* Bb = smem + NP * ABYTES + p * BBYTES;
      for (int u = tid; u < KT * 64 * 4; u += 256) {
        const int R = u >> 2, ic = u & 3;
        const int tap = R >> 6, o = R & 63;
        const uint4 val = *(const uint4*)(wsrc + ((size_t)(o0 + o) * KT + tap) * Cinp + (ib << 5) + ic * 8);
        *(uint4*)(Bb + R * 64 + ((ic ^ ((R >> 1) & 3)) * 16)) = val;
      }
    }
    __syncthreads();
    // ---------------- MFMA ----------------
    #pragma unroll
    for (int tap = 0; tap < KT; ++tap) {
      f16x8 af[NP][4], bf[NP][4];
      #pragma unroll
      for (int ti = 0; ti < 4; ++ti) {
        const int r  = wv * 64 + ti * 16 + lm + tap;
        const int by = r * 64 + ((g ^ ((r >> 1) & 3)) * 16);
        af[0][ti] = *(const f16x8*)(smem + by);
        if constexpr (SPLIT) af[1][ti] = *(const f16x8*)(smem + ABYTES + by);
      }
      #pragma unroll
      for (int oi = 0; oi < 4; ++oi) {
        const int R  = tap * 64 + oi * 16 + lm;
        const int by = R * 64 + ((g ^ ((R >> 1) & 3)) * 16);
        bf[0][oi] = *(const f16x8*)(smem + NP * ABYTES + by);
        if constexpr (SPLIT) bf[1][oi] = *(const f16x8*)(smem + NP * ABYTES + BBYTES + by);
      }
      #pragma unroll
      for (int ti = 0; ti < 4; ++ti) {
        #pragma unroll
        for (int oi = 0; oi < 4; ++oi) {
          acc[ti][oi] = __builtin_amdgcn_mfma_f32_16x16x32_f16(af[0][ti], bf[0][oi], acc[ti][oi], 0, 0, 0);
          if constexpr (SPLIT) {
            acc2[ti][oi] = __builtin_amdgcn_mfma_f32_16x16x32_f16(af[0][ti], bf[1][oi], acc2[ti][oi], 0, 0, 0);
            acc2[ti][oi] = __builtin_amdgcn_mfma_f32_16x16x32_f16(af[1][ti], bf[0][oi], acc2[ti][oi], 0, 0, 0);
          }
        }
      }
    }
    __syncthreads();
  }
  // ---------------- store (D: col=lane&15 -> o, row=(lane>>4)*4+reg -> t) ----------------
  #pragma unroll
  for (int oi = 0; oi < 4; ++oi) {
    const int o_g = o0 + oi * 16 + lm;
    if (o_g < Cout) {
      const float bv = bias ? bias[o_g] : 0.f;
      #pragma unroll
      for (int ti = 0; ti < 4; ++ti) {
        f32x4 v = acc[ti][oi];
        if constexpr (SPLIT) v += acc2[ti][oi] * (1.f / 4096.f);
        v += bv;
        const int t = t0 + wv * 64 + ti * 16 + g * 4;
        *(f32x4*)(out + ((size_t)b * Cout + o_g) * T + t) = v;
      }
    }
  }
}

// ======================= helper kernels =======================

// normalize codebook rows (512) and speaker rows (64), dim 128 (fp32 out)
__global__ void norm_rows_k(const float* __restrict__ cb, const float* __restrict__ spk,
                            float* __restrict__ cbn, float* __restrict__ sn) {
  int r = blockIdx.x;
  int c = threadIdx.x;   // 128 threads
  const float* src;
  float* dst;
  if (r < 512) { src = cb + (size_t)r * 128;          dst = cbn + (size_t)r * 128; }
  else         { src = spk + (size_t)(r - 512) * 128; dst = sn + (size_t)(r - 512) * 128; }
  float v = src[c];
  float p = v * v;
  for (int off = 32; off; off >>= 1) p += __shfl_down(p, off);
  __shared__ float ls[2];
  if ((c & 63) == 0) ls[c >> 6] = p;
  __syncthreads();
  float ss = ls[0] + ls[1];
  dst[c] = v * (1.f / sqrtf(ss + 1e-12f));
}

// yvh[b][c][t] = (half)sn[y[b][t]][c]   (full batch of 16)
__global__ void yv_fill_h_k(const int* __restrict__ y, const float* __restrict__ sn,
                            half_t* __restrict__ yvh) {
  const int T = T_LEN;
  size_t idx = (size_t)blockIdx.x * 256 + threadIdx.x;
  size_t total = (size_t)16 * 128 * T;
  if (idx >= total) return;
  int t = idx & (T - 1);
  int c = (idx / T) & 127;
  int b = idx / ((size_t)128 * T);
  int yb = y[(size_t)b * T + t];
  yvh[idx] = (half_t)sn[(size_t)yb * 128 + c];
}

// fp32 -> (hi, lo*4096) fp16 pair
__global__ void split_pair_k(const float* __restrict__ src, half_t* __restrict__ h,
                             half_t* __restrict__ l, size_t n) {
  size_t i = (size_t)blockIdx.x * 256 + threadIdx.x;
  if (i >= n) return;
  float v = src[i];
  half_t hh = (half_t)v;
  h[i] = hh;
  l[i] = (half_t)((v - (float)hh) * 4096.f);
}

// weight prep -> wT[o][k][i] fp16 pair, o<Coutp (pad 0), i<Cinp (pad 0)
// mode 0: src = w[O][I][K] (Conv1d / plain [O][I] when K==1)
// mode 1: src = w[I][O][K] ConvTranspose1d, k flipped
__global__ void prep_w_split_k(const float* __restrict__ src, half_t* __restrict__ h,
                               half_t* __restrict__ l, int Cin, int Cout, int K,
                               int Cinp, int Coutp, int mode) {
  size_t idx = (size_t)blockIdx.x * 256 + threadIdx.x;
  size_t total = (size_t)Coutp * K * Cinp;
  if (idx >= total) return;
  int o = idx / ((size_t)K * Cinp);
  int r = idx % ((size_t)K * Cinp);
  int k = r / Cinp, i = r % Cinp;
  float v = 0.f;
  if (o < Cout && i < Cin)
    v = (mode == 0) ? src[((size_t)o * Cin + i) * K + k]
                    : src[((size_t)i * Cout + o) * K + (K - 1 - k)];
  half_t hh = (half_t)v;
  h[idx] = hh;
  l[idx] = (half_t)((v - (float)hh) * 4096.f);
}

// GroupNorm(1,C) deterministic partials: grid (GN_NP, bc)
__global__ __launch_bounds__(256) void gn_stats_k(const float* __restrict__ x,
                                                  float* __restrict__ part, int C) {
  const int T = T_LEN;
  int b = blockIdx.y;
  size_t total = (size_t)C * T;
  size_t per = total / GN_NP;
  const float* base = x + (size_t)b * total + (size_t)blockIdx.x * per;
  float s = 0.f, ss = 0.f;
  for (size_t i = threadIdx.x; i < per; i += 256) {
    float v = base[i];
    s += v; ss += v * v;
  }
  for (int off = 32; off; off >>= 1) { s += __shfl_down(s, off); ss += __shfl_down(ss, off); }
  __shared__ float l1[4], l2[4];
  int w = threadIdx.x >> 6;
  if ((threadIdx.x & 63) == 0) { l1[w] = s; l2[w] = ss; }
  __syncthreads();
  if (threadIdx.x == 0) {
    part[((size_t)b * GN_NP + blockIdx.x) * 2]     = l1[0] + l1[1] + l1[2] + l1[3];
    part[((size_t)b * GN_NP + blockIdx.x) * 2 + 1] = l2[0] + l2[1] + l2[2] + l2[3];
  }
}

__global__ void gn_finalize_k(const float* __restrict__ part, float* __restrict__ stats,
                              float invN) {
  int b = blockIdx.x;
  int p = threadIdx.x;   // 128
  float s  = part[((size_t)b * GN_NP + p) * 2];
  float ss = part[((size_t)b * GN_NP + p) * 2 + 1];
  for (int off = 32; off; off >>= 1) { s += __shfl_down(s, off); ss += __shfl_down(ss, off); }
  __shared__ float l1[2], l2[2];
  if ((p & 63) == 0) { l1[p >> 6] = s; l2[p >> 6] = ss; }
  __syncthreads();
  if (p == 0) {
    float S = l1[0] + l1[1], SS = l2[0] + l2[1];
    float m = S * invN;
    float var = fmaxf(SS * invN - m * m, 0.f);
    stats[b * 2]     = m;
    stats[b * 2 + 1] = 1.f / sqrtf(var + 1e-5f);
  }
}

// GN + LeakyReLU -> fp16 split pair; grid (T/256, C, bc)
__global__ void gn_lrelu_split_k(const float* __restrict__ x, half_t* __restrict__ h,
                                 half_t* __restrict__ l, const float* __restrict__ g,
                                 const float* __restrict__ bt,
                                 const float* __restrict__ stats, int C) {
  const int T = T_LEN;
  int b = blockIdx.z, c = blockIdx.y;
  int t = blockIdx.x * 256 + threadIdx.x;
  float m = stats[b * 2], rs = stats[b * 2 + 1];
  size_t i = ((size_t)b * C + c) * T + t;
  float v = (x[i] - m) * rs * g[c] + bt[c];
  v = v >= 0.f ? v : 0.02f * v;
  half_t hh = (half_t)v;
  h[i] = hh;
  l[i] = (half_t)((v - (float)hh) * 4096.f);
}

// GN + GLU -> fp16 into dqa[b][640][T] rows [0,512); grid (T/256, 512, bc)
__global__ void gn_glu_h_k(const float* __restrict__ x, half_t* __restrict__ dqa,
                           const float* __restrict__ g, const float* __restrict__ bt,
                           const float* __restrict__ stats) {
  const int T = T_LEN, C = 1024, Co = 512;
  int b = blockIdx.z, c = blockIdx.y;
  int t = blockIdx.x * 256 + threadIdx.x;
  float m = stats[b * 2], rs = stats[b * 2 + 1];
  float a  = (x[((size_t)b * C + c) * T + t]      - m) * rs * g[c]      + bt[c];
  float gt = (x[((size_t)b * C + Co + c) * T + t] - m) * rs * g[Co + c] + bt[Co + c];
  dqa[((size_t)b * 640 + c) * T + t] = (half_t)(a * (1.f / (1.f + expf(-gt))));
}

// argmax over 512 codes; sims [bc][512][T]
__global__ void argmax_k(const float* __restrict__ sims, int* __restrict__ idx) {
  const int T = T_LEN;
  int b = blockIdx.y;
  int t = blockIdx.x * 256 + threadIdx.x;
  float best = -3.4e38f;
  int bi = 0;
  for (int k = 0; k < 512; ++k) {
    float v = sims[((size_t)b * 512 + k) * T + t];
    if (v > best) { best = v; bi = k; }
  }
  idx[(size_t)b * T + t] = bi;
}

// dq1[bc][256][T] fp16: c<128 -> cbh[idx[b][t]][c], else yvh[b][c-128][t]
__global__ void zqcat_h_k(const int* __restrict__ idx, const half_t* __restrict__ cbh,
                          const half_t* __restrict__ yvh, half_t* __restrict__ dq1, int nb) {
  const int T = T_LEN;
  size_t i = (size_t)blockIdx.x * 256 + threadIdx.x;
  size_t total = (size_t)nb * 256 * T;
  if (i >= total) return;
  int t = i & (T - 1);
  int c = (i / T) & 255;
  int b = i / ((size_t)256 * T);
  half_t v;
  if (c < 128) {
    int ki = idx[(size_t)b * T + t];
    v = cbh[(size_t)ki * 128 + c];
  } else {
    v = yvh[((size_t)b * 128 + (c - 128)) * T + t];
  }
  dq1[i] = v;
}

// dqa[b][512+c][T] = yvh[b][c][T]
__global__ void ych_copy_k(const half_t* __restrict__ yvh, half_t* __restrict__ dqa, int nb) {
  const int T = T_LEN;
  size_t i = (size_t)blockIdx.x * 256 + threadIdx.x;
  size_t total = (size_t)nb * 128 * T;
  if (i >= total) return;
  int t = i & (T - 1);
  int c = (i / T) & 127;
  int b = i / ((size_t)128 * T);
  dqa[((size_t)b * 640 + 512 + c) * T + t] = yvh[i];
}

// ======================= host side =======================

extern "C" void kernel_launch(void* const* d_in, const int* in_sizes, int n_in,
                              void* d_out, int out_size, void* d_ws, size_t ws_size,
                              hipStream_t stream) {
  const int T = T_LEN;
  const float* x    = (const float*)d_in[0];
  const int*   y    = (const int*)d_in[1];
  const float* spk  = (const float*)d_in[2];
  const float* cb   = (const float*)d_in[3];
  const float* ew0  = (const float*)d_in[4];
  const float* eb0  = (const float*)d_in[5];
  const float* eg0  = (const float*)d_in[6];
  const float* et0  = (const float*)d_in[7];
  const float* ew1  = (const float*)d_in[8];
  const float* eb1  = (const float*)d_in[9];
  const float* eg1  = (const float*)d_in[10];
  const float* et1  = (const float*)d_in[11];
  const float* ew2  = (const float*)d_in[12];
  const float* eb2  = (const float*)d_in[13];
  const float* eg2  = (const float*)d_in[14];
  const float* et2  = (const float*)d_in[15];
  const float* mw   = (const float*)d_in[16];
  const float* mb   = (const float*)d_in[17];
  const float* dw0  = (const float*)d_in[18];
  const float* db0  = (const float*)d_in[19];
  const float* dg0  = (const float*)d_in[20];
  const float* dt0  = (const float*)d_in[21];
  const float* dw1  = (const float*)d_in[22];
  const float* db1  = (const float*)d_in[23];
  const float* dg1  = (const float*)d_in[24];
  const float* dt1  = (const float*)d_in[25];
  const float* dw2  = (const float*)d_in[26];
  const float* db2  = (const float*)d_in[27];
  float* out = (float*)d_out;
  (void)in_sizes; (void)n_in; (void)out_size;

  // ---- weight plane element counts (fp16, padded) ----
  const size_t PW_E0 = (size_t)1024 * 5 * 64;
  const size_t PW_E1 = (size_t)512 * 5 * 1024;
  const size_t PW_E2 = (size_t)512 * 5 * 512;
  const size_t PW_M  = (size_t)128 * 1 * 512;
  const size_t PW_CB = (size_t)512 * 1 * 128;
  const size_t PW_D0 = (size_t)1024 * 5 * 256;
  const size_t PW_D1 = (size_t)1024 * 5 * 640;
  const size_t PW_D2 = (size_t)64 * 5 * 640;
  const size_t PW_MAX = PW_D1;

  auto al = [](size_t bytes) { return (bytes + 255) & ~(size_t)255; };
  const size_t fixedB = al(512 * 128 * 4) + al(64 * 128 * 4) +              // cbn, sn
                        al((size_t)16 * 128 * T * 2) +                       // yvh
                        2 * al((size_t)16 * 39 * T * 2) +                    // xh, xl
                        al((size_t)16 * T * 4) +                             // idx
                        al((size_t)16 * GN_NP * 2 * 4) + al(256);            // part, stats
  const size_t wfullB = 2 * (al(PW_E0 * 2) + al(PW_E1 * 2) + al(PW_E2 * 2) + al(PW_M * 2) +
                             al(PW_CB * 2) + al(PW_D0 * 2) + al(PW_D1 * 2) + al(PW_D2 * 2));
  const size_t wshB = 2 * al(PW_MAX * 2);
  auto chunkB = [&](int c) {
    return al((size_t)c * 1024 * T * 4) +        // A32
           al((size_t)c * 512 * T * 4) +         // C32
           2 * al((size_t)c * 1024 * T * 2) +    // H1 pair
           4 * al((size_t)c * 512 * T * 2) +     // H2, H3 pairs
           2 * al((size_t)c * 128 * T * 2) +     // zh, zl
           al((size_t)c * 256 * T * 2) +         // dq1
           al((size_t)c * 640 * T * 2);          // dqa
  };

  int bc = 0;
  bool shw = false;
  {
    const int cands[5] = {16, 8, 4, 2, 1};
    for (int i = 0; i < 5 && !bc; ++i)
      if (fixedB + wfullB + chunkB(cands[i]) <= ws_size) bc = cands[i];
    if (!bc) {
      shw = true;
      for (int i = 0; i < 5 && !bc; ++i)
        if (fixedB + wshB + chunkB(cands[i]) <= ws_size) bc = cands[i];
    }
    if (!bc) return;
  }

  char* base = (char*)d_ws;
  size_t off = 0;
  auto takeB = [&](size_t bytes) -> char* {
    char* r = base + off;
    off += al(bytes);
    return r;
  };
  float* cbn   = (float*)takeB(512 * 128 * 4);
  float* sn    = (float*)takeB(64 * 128 * 4);
  half_t* yvh  = (half_t*)takeB((size_t)16 * 128 * T * 2);
  half_t* xh   = (half_t*)takeB((size_t)16 * 39 * T * 2);
  half_t* xl   = (half_t*)takeB((size_t)16 * 39 * T * 2);
  int*   idx   = (int*)takeB((size_t)16 * T * 4);
  float* part  = (float*)takeB((size_t)16 * GN_NP * 2 * 4);
  float* stats = (float*)takeB(256);

  struct WP { half_t *h, *l; };
  WP we0p, we1p, we2p, wmp, cbp, wd0p, wd1p, wd2p;
  if (!shw) {
    auto tw = [&](size_t pe) { WP w; w.h = (half_t*)takeB(pe * 2); w.l = (half_t*)takeB(pe * 2); return w; };
    we0p = tw(PW_E0); we1p = tw(PW_E1); we2p = tw(PW_E2); wmp = tw(PW_M);
    cbp = tw(PW_CB); wd0p = tw(PW_D0); wd1p = tw(PW_D1); wd2p = tw(PW_D2);
  } else {
    WP sh;
    sh.h = (half_t*)takeB(PW_MAX * 2);
    sh.l = (half_t*)takeB(PW_MAX * 2);
    we0p = we1p = we2p = wmp = cbp = wd0p = wd1p = wd2p = sh;
  }
  float* A32  = (float*)takeB((size_t)bc * 1024 * T * 4);
  float* C32  = (float*)takeB((size_t)bc * 512 * T * 4);
  half_t* H1h = (half_t*)takeB((size_t)bc * 1024 * T * 2);
  half_t* H1l = (half_t*)takeB((size_t)bc * 1024 * T * 2);
  half_t* H2h = (half_t*)takeB((size_t)bc * 512 * T * 2);
  half_t* H2l = (half_t*)takeB((size_t)bc * 512 * T * 2);
  half_t* H3h = (half_t*)takeB((size_t)bc * 512 * T * 2);
  half_t* H3l = (half_t*)takeB((size_t)bc * 512 * T * 2);
  half_t* zh  = (half_t*)takeB((size_t)bc * 128 * T * 2);
  half_t* zl  = (half_t*)takeB((size_t)bc * 128 * T * 2);
  half_t* dq1 = (half_t*)takeB((size_t)bc * 256 * T * 2);
  half_t* dqa = (half_t*)takeB((size_t)bc * 640 * T * 2);

  dim3 blk(256);
  auto nblk = [](size_t total) { return dim3((unsigned)((total + 255) / 256)); };
  auto prepW = [&](const float* src, WP w, int Ci, int Co, int K, int Cip, int Cop, int mode) {
    size_t tot = (size_t)Cop * K * Cip;
    prep_w_split_k<<<nblk(tot), blk, 0, stream>>>(src, w.h, w.l, Ci, Co, K, Cip, Cop, mode);
  };

  // ---- one-time prep ----
  norm_rows_k<<<576, 128, 0, stream>>>(cb, spk, cbn, sn);
  yv_fill_h_k<<<nblk((size_t)16 * 128 * T), blk, 0, stream>>>(y, sn, yvh);
  split_pair_k<<<nblk((size_t)16 * 39 * T), blk, 0, stream>>>(x, xh, xl, (size_t)16 * 39 * T);
  if (!shw) {
    prepW(ew0, we0p, 39, 1024, 5, 64, 1024, 0);
    prepW(ew1, we1p, 1024, 512, 5, 1024, 512, 0);
    prepW(ew2, we2p, 512, 512, 5, 512, 512, 0);
    prepW(mw,  wmp, 512, 128, 1, 512, 128, 0);
    prepW(cbn, cbp, 128, 512, 1, 128, 512, 0);
    prepW(dw0, wd0p, 256, 1024, 5, 256, 1024, 1);
    prepW(dw1, wd1p, 640, 1024, 5, 640, 1024, 1);
    prepW(dw2, wd2p, 640, 39, 5, 640, 64, 1);
  }

  for (int b0 = 0; b0 < 16; b0 += bc) {
    const half_t* xhc = xh + (size_t)b0 * 39 * T;
    const half_t* xlc = xl + (size_t)b0 * 39 * T;
    const half_t* yvc = yvh + (size_t)b0 * 128 * T;
    int* idxc = idx + (size_t)b0 * T;
    float* outc = out + (size_t)b0 * 39 * T;

    // encoder 0: 39 -> 1024
    if (shw) prepW(ew0, we0p, 39, 1024, 5, 64, 1024, 0);
    conv_mfma<1, 5><<<dim3(8, 16, bc), blk, 0, stream>>>(xhc, xlc, we0p.h, we0p.l, eb0, A32, 39, 64, 1024);
    gn_stats_k<<<dim3(GN_NP, bc), blk, 0, stream>>>(A32, part, 1024);
    gn_finalize_k<<<bc, 128, 0, stream>>>(part, stats, 1.f / (1024.f * T));
    gn_lrelu_split_k<<<dim3(8, 1024, bc), blk, 0, stream>>>(A32, H1h, H1l, eg0, et0, stats, 1024);

    // encoder 1: 1024 -> 512
    if (shw) prepW(ew1, we1p, 1024, 512, 5, 1024, 512, 0);
    conv_mfma<1, 5><<<dim3(8, 8, bc), blk, 0, stream>>>(H1h, H1l, we1p.h, we1p.l, eb1, C32, 1024, 1024, 512);
    gn_stats_k<<<dim3(GN_NP, bc), blk, 0, stream>>>(C32, part, 512);
    gn_finalize_k<<<bc, 128, 0, stream>>>(part, stats, 1.f / (512.f * T));
    gn_lrelu_split_k<<<dim3(8, 512, bc), blk, 0, stream>>>(C32, H2h, H2l, eg1, et1, stats, 512);

    // encoder 2: 512 -> 512
    if (shw) prepW(ew2, we2p, 512, 512, 5, 512, 512, 0);
    conv_mfma<1, 5><<<dim3(8, 8, bc), blk, 0, stream>>>(H2h, H2l, we2p.h, we2p.l, eb2, C32, 512, 512, 512);
    gn_stats_k<<<dim3(GN_NP, bc), blk, 0, stream>>>(C32, part, 512);
    gn_finalize_k<<<bc, 128, 0, stream>>>(part, stats, 1.f / (512.f * T));
    gn_lrelu_split_k<<<dim3(8, 512, bc), blk, 0, stream>>>(C32, H3h, H3l, eg2, et2, stats, 512);

    // bottleneck 1x1: 512 -> 128 (z into A32)
    if (shw) prepW(mw, wmp, 512, 128, 1, 512, 128, 0);
    conv_mfma<1, 1><<<dim3(8, 2, bc), blk, 0, stream>>>(H3h, H3l, wmp.h, wmp.l, mb, A32, 512, 512, 128);
    split_pair_k<<<nblk((size_t)bc * 128 * T), blk, 0, stream>>>(A32, zh, zl, (size_t)bc * 128 * T);

    // VQ sims: z . cbn^T -> C32 [bc][512][T]
    if (shw) prepW(cbn, cbp, 128, 512, 1, 128, 512, 0);
    conv_mfma<1, 1><<<dim3(8, 8, bc), blk, 0, stream>>>(zh, zl, cbp.h, cbp.l, nullptr, C32, 128, 128, 512);
    argmax_k<<<dim3(8, bc), blk, 0, stream>>>(C32, idxc);

    // decoder input 1: concat(zq, yv) fp16
    zqcat_h_k<<<nblk((size_t)bc * 256 * T), blk, 0, stream>>>(idxc, cbp.h, yvc, dq1, bc);
    ych_copy_k<<<nblk((size_t)bc * 128 * T), blk, 0, stream>>>(yvc, dqa, bc);

    // decoder 0: 256 -> 1024, GN+GLU -> dqa[0..512)
    if (shw) prepW(dw0, wd0p, 256, 1024, 5, 256, 1024, 1);
    conv_mfma<0, 5><<<dim3(8, 16, bc), blk, 0, stream>>>(dq1, nullptr, wd0p.h, nullptr, db0, A32, 256, 256, 1024);
    gn_stats_k<<<dim3(GN_NP, bc), blk, 0, stream>>>(A32, part, 1024);
    gn_finalize_k<<<bc, 128, 0, stream>>>(part, stats, 1.f / (1024.f * T));
    gn_glu_h_k<<<dim3(8, 512, bc), blk, 0, stream>>>(A32, dqa, dg0, dt0, stats);

    // decoder 1: 640 -> 1024, GN+GLU -> dqa[0..512)
    if (shw) prepW(dw1, wd1p, 640, 1024, 5, 640, 1024, 1);
    conv_mfma<0, 5><<<dim3(8, 16, bc), blk, 0, stream>>>(dqa, nullptr, wd1p.h, nullptr, db1, A32, 640, 640, 1024);
    gn_stats_k<<<dim3(GN_NP, bc), blk, 0, stream>>>(A32, part, 1024);
    gn_finalize_k<<<bc, 128, 0, stream>>>(part, stats, 1.f / (1024.f * T));
    gn_glu_h_k<<<dim3(8, 512, bc), blk, 0, stream>>>(A32, dqa, dg1, dt1, stats);

    // decoder 2: 640 -> 39 -> out
    if (shw) prepW(dw2, wd2p, 640, 39, 5, 640, 64, 1);
    conv_mfma<0, 5><<<dim3(8, 1, bc), blk, 0, stream>>>(dqa, nullptr, wd2p.h, nullptr, db2, outc, 640, 640, 39);
  }
}

// Round 5
// 2071.595 us; speedup vs baseline: 5.1180x; 1.8873x over previous
//
#include <hip/hip_runtime.h>
#include <math.h>

#define T_LEN 2048
#define MAXP  256   // max GN partial slots per sample

typedef _Float16 half_t;
typedef __attribute__((ext_vector_type(8))) _Float16 f16x8;
typedef __attribute__((ext_vector_type(4))) float f32x4;

static __device__ inline float h2f(ushort u) { half_t h; __builtin_memcpy(&h, &u, 2); return (float)h; }
static __device__ inline ushort f2h(float f) { half_t h = (half_t)f; ushort u; __builtin_memcpy(&u, &h, 2); return u; }

// ===================== conv as implicit GEMM via MFMA =====================
// Layout: activations [b][t][c] (c padded to mult of 32, 2B); weights [o][tap][i].
// A: M=t (BT/block), K=ch (32/step); B: N=o (64/block). 256 thr = 4 waves in t.
// SPLIT=1: (hi, lo*4096) fp16 pairs, 3-term MFMA (~fp32 accuracy).
// MODE 0: pair out [t][c] + stats | 3: h-only out + stats | 1: fp32 [t][c], no stats
//      | 2: fp32 [c][t], o<Cout only, no stats (final layer)
template<int SPLIT, int KT, int BT, int MODE>
__global__ __launch_bounds__(256, 2) void conv_mfma(
    const half_t* __restrict__ inH, const half_t* __restrict__ inL,
    const half_t* __restrict__ wH, const half_t* __restrict__ wL,
    const float* __restrict__ bias,
    half_t* __restrict__ outH, half_t* __restrict__ outL,
    float* __restrict__ outF, float* __restrict__ part,
    int Cin, int Cout, int ldOut)
{
  constexpr int T  = T_LEN;
  constexpr int PAD = (KT - 1) / 2;
  constexpr int RA = BT + KT - 1;
  constexpr int TI = BT / 64;
  constexpr int NP = SPLIT ? 2 : 1;
  constexpr int ABY = RA * 64;
  constexpr int BBY = KT * 64 * 64;
  __shared__ __align__(16) char smem[(ABY + BBY) * NP];
  __shared__ float red1[4], red2[4];

  const int tid = threadIdx.x;
  const int t0 = blockIdx.x * BT;
  const int o0 = blockIdx.y * 64;
  const int b  = blockIdx.z;
  const int l  = tid & 63, wv = tid >> 6, lm = l & 15, g = l >> 4;

  f32x4 acc[TI][4] = {};
  f32x4 acc2[TI][4] = {};

  const int nib = Cin >> 5;
  for (int ib = 0; ib < nib; ++ib) {
    // ---- stage A: rows r -> t0+r-PAD, 64B of channels, chunk-XOR swizzle ----
    #pragma unroll
    for (int p = 0; p < NP; ++p) {
      const half_t* src = p ? inL : inH;
      char* Ab = smem + p * ABY;
      for (int u = tid; u < RA * 4; u += 256) {
        const int r = u >> 2, q = u & 3;
        const int t = t0 + r - PAD;
        uint4 v = make_uint4(0, 0, 0, 0);
        if (t >= 0 && t < T)
          v = *(const uint4*)(src + ((size_t)b * T + t) * (size_t)Cin + (ib << 5) + q * 8);
        *(uint4*)(Ab + r * 64 + ((q ^ ((r >> 1) & 3)) << 4)) = v;
      }
    }
    // ---- stage B: weights rows R=(tap,o) ----
    #pragma unroll
    for (int p = 0; p < NP; ++p) {
      const half_t* ws = p ? wL : wH;
      char* Bb = smem + NP * ABY + p * BBY;
      for (int u = tid; u < KT * 64 * 4; u += 256) {
        const int R = u >> 2, q = u & 3;
        const int tap = R >> 6, o = R & 63;
        uint4 v = *(const uint4*)(ws + ((size_t)(o0 + o) * KT + tap) * (size_t)Cin + (ib << 5) + q * 8);
        *(uint4*)(Bb + R * 64 + ((q ^ ((R >> 1) & 3)) << 4)) = v;
      }
    }
    __syncthreads();
    // ---- MFMA ----
    #pragma unroll
    for (int tap = 0; tap < KT; ++tap) {
      f16x8 af[NP][TI], bf[NP][4];
      #pragma unroll
      for (int ti = 0; ti < TI; ++ti) {
        const int r = wv * (TI * 16) + ti * 16 + lm + tap;
        const int by = r * 64 + ((g ^ ((r >> 1) & 3)) << 4);
        af[0][ti] = *(const f16x8*)(smem + by);
        if constexpr (SPLIT) af[1][ti] = *(const f16x8*)(smem + ABY + by);
      }
      #pragma unroll
      for (int oi = 0; oi < 4; ++oi) {
        const int R = tap * 64 + oi * 16 + lm;
        const int by = R * 64 + ((g ^ ((R >> 1) & 3)) << 4);
        bf[0][oi] = *(const f16x8*)(smem + NP * ABY + by);
        if constexpr (SPLIT) bf[1][oi] = *(const f16x8*)(smem + NP * ABY + BBY + by);
      }
      #pragma unroll
      for (int ti = 0; ti < TI; ++ti)
        #pragma unroll
        for (int oi = 0; oi < 4; ++oi) {
          acc[ti][oi] = __builtin_amdgcn_mfma_f32_16x16x32_f16(af[0][ti], bf[0][oi], acc[ti][oi], 0, 0, 0);
          if constexpr (SPLIT) {
            acc2[ti][oi] = __builtin_amdgcn_mfma_f32_16x16x32_f16(af[0][ti], bf[1][oi], acc2[ti][oi], 0, 0, 0);
            acc2[ti][oi] = __builtin_amdgcn_mfma_f32_16x16x32_f16(af[1][ti], bf[0][oi], acc2[ti][oi], 0, 0, 0);
          }
        }
    }
    __syncthreads();
  }

  // ---- epilogue: bias, store, fused GN partial stats ----
  float s = 0.f, ss = 0.f;
  #pragma unroll
  for (int oi = 0; oi < 4; ++oi) {
    const int o = o0 + oi * 16 + lm;
    const float bv = (bias != nullptr && o < Cout) ? bias[o] : 0.f;
    #pragma unroll
    for (int ti = 0; ti < TI; ++ti) {
      f32x4 v = acc[ti][oi];
      if constexpr (SPLIT) v += acc2[ti][oi] * (1.f / 4096.f);
      v += bv;
      const int tbase = t0 + wv * (TI * 16) + ti * 16 + g * 4;
      if constexpr (MODE == 0 || MODE == 3) {
        #pragma unroll
        for (int j = 0; j < 4; ++j) {
          const float vv = v[j];
          s += vv; ss += vv * vv;
          const size_t oidx = ((size_t)b * T + (tbase + j)) * (size_t)ldOut + o;
          const half_t hh = (half_t)vv;
          outH[oidx] = hh;
          if constexpr (MODE == 0) outL[oidx] = (half_t)((vv - (float)hh) * 4096.f);
        }
      } else if constexpr (MODE == 1) {
        #pragma unroll
        for (int j = 0; j < 4; ++j)
          outF[((size_t)b * T + (tbase + j)) * (size_t)ldOut + o] = v[j];
      } else {
        if (o < Cout) {
          #pragma unroll
          for (int j = 0; j < 4; ++j)
            outF[((size_t)b * Cout + o) * (size_t)T + (tbase + j)] = v[j];
        }
      }
    }
  }
  if constexpr (MODE == 0 || MODE == 3) {
    for (int off = 32; off; off >>= 1) { s += __shfl_down(s, off); ss += __shfl_down(ss, off); }
    if (l == 0) { red1[wv] = s; red2[wv] = ss; }
    __syncthreads();
    if (tid == 0) {
      const size_t slot = (size_t)b * MAXP + blockIdx.y * gridDim.x + blockIdx.x;
      part[slot * 2]     = red1[0] + red1[1] + red1[2] + red1[3];
      part[slot * 2 + 1] = red2[0] + red2[1] + red2[2] + red2[3];
    }
  }
}

// ======================= helper kernels =======================

// normalize codebook rows (512) and speaker rows (64), dim 128
__global__ void norm_rows_k(const float* __restrict__ cb, const float* __restrict__ spk,
                            float* __restrict__ cbn, float* __restrict__ sn) {
  int r = blockIdx.x;
  int c = threadIdx.x;   // 128
  const float* src; float* dst;
  if (r < 512) { src = cb + (size_t)r * 128;          dst = cbn + (size_t)r * 128; }
  else         { src = spk + (size_t)(r - 512) * 128; dst = sn + (size_t)(r - 512) * 128; }
  float v = src[c];
  float p = v * v;
  for (int off = 32; off; off >>= 1) p += __shfl_down(p, off);
  __shared__ float ls[2];
  if ((c & 63) == 0) ls[c >> 6] = p;
  __syncthreads();
  dst[c] = v * (1.f / sqrtf(ls[0] + ls[1] + 1e-12f));
}

// W'[k][c] = sum_d cbn[k][d]*mw[d][c]   (mw: [128][512][1])
__global__ void compose_vq_k(const float* __restrict__ cbn, const float* __restrict__ mw,
                             float* __restrict__ Wf) {
  int idx = blockIdx.x * 256 + threadIdx.x;   // 512*512
  int k = idx >> 9, c = idx & 511;
  float s = 0.f;
  for (int d = 0; d < 128; ++d) s = fmaf(cbn[k * 128 + d], mw[d * 512 + c], s);
  Wf[idx] = s;
}
__global__ void compose_vqb_k(const float* __restrict__ cbn, const float* __restrict__ mb,
                              float* __restrict__ vqb) {
  int k = blockIdx.x * 256 + threadIdx.x;
  if (k >= 512) return;
  float s = 0.f;
  for (int d = 0; d < 128; ++d) s = fmaf(cbn[k * 128 + d], mb[d], s);
  vqb[k] = s;
}

// weight prep -> [o][tap][i] fp16 pair (l nullable), padded Cinp/Coutp
// mode 0: src w[O][I][K]; mode 1: src w[I][O][K], tap flipped (ConvTranspose)
__global__ void prep_w_split_k(const float* __restrict__ src, half_t* __restrict__ h,
                               half_t* __restrict__ l, int Cin, int Cout, int K,
                               int Cinp, int Coutp, int mode) {
  size_t idx = (size_t)blockIdx.x * 256 + threadIdx.x;
  size_t total = (size_t)Coutp * K * Cinp;
  if (idx >= total) return;
  int o = idx / ((size_t)K * Cinp);
  int r = idx % ((size_t)K * Cinp);
  int k = r / Cinp, i = r % Cinp;
  float v = 0.f;
  if (o < Cout && i < Cin)
    v = (mode == 0) ? src[((size_t)o * Cin + i) * K + k]
                    : src[((size_t)i * Cout + o) * K + (K - 1 - k)];
  half_t hh = (half_t)v;
  h[idx] = hh;
  if (l) l[idx] = (half_t)((v - (float)hh) * 4096.f);
}

// x [bc][39][T] fp32 -> xpair [bc][t][64] (pad 0), coalesced read
__global__ void xsplit_k(const float* __restrict__ x, half_t* __restrict__ xh,
                         half_t* __restrict__ xl, int nb) {
  size_t i = (size_t)blockIdx.x * 256 + threadIdx.x;
  if (i >= (size_t)nb * 64 * T_LEN) return;
  int t = (int)(i & (T_LEN - 1));
  int c = (int)((i >> 11) & 63);
  int b = (int)(i >> 17);
  float v = (c < 39) ? x[((size_t)b * 39 + c) * T_LEN + t] : 0.f;
  half_t hh = (half_t)v;
  size_t o = ((size_t)b * T_LEN + t) * 64 + c;
  xh[o] = hh;
  xl[o] = (half_t)((v - (float)hh) * 4096.f);
}

// GN (stats from part, reduced in-block) + LeakyReLU, in-place on pair [t][C]
__global__ __launch_bounds__(256) void gn_lrelu_pair_k(
    half_t* __restrict__ h, half_t* __restrict__ l,
    const float* __restrict__ g, const float* __restrict__ bt,
    const float* __restrict__ part, int C, int P, float invN) {
  const int b = blockIdx.y, tid = threadIdx.x;
  float s = 0.f, ss = 0.f;
  if (tid < P) { s = part[((size_t)b * MAXP + tid) * 2]; ss = part[((size_t)b * MAXP + tid) * 2 + 1]; }
  for (int off = 32; off; off >>= 1) { s += __shfl_down(s, off); ss += __shfl_down(ss, off); }
  __shared__ float l1[4], l2[4], smv[2];
  if ((tid & 63) == 0) { l1[tid >> 6] = s; l2[tid >> 6] = ss; }
  __syncthreads();
  if (tid == 0) {
    float S = l1[0] + l1[1] + l1[2] + l1[3], SS = l2[0] + l2[1] + l2[2] + l2[3];
    float m = S * invN;
    float var = fmaxf(SS * invN - m * m, 0.f);
    smv[0] = m; smv[1] = 1.f / sqrtf(var + 1e-5f);
  }
  __syncthreads();
  const float m = smv[0], rs = smv[1];
  size_t i0 = ((size_t)blockIdx.x * 256 + tid) * 4;
  const int c = (int)(i0 & (size_t)(C - 1));
  size_t off = (size_t)b * T_LEN * C + i0;
  ushort4 hv = *(ushort4*)(h + off);
  ushort4 lv = *(ushort4*)(l + off);
  float4 gg = *(const float4*)(g + c);
  float4 bb = *(const float4*)(bt + c);
  float vin[4] = { h2f(hv.x) + h2f(lv.x) * (1.f/4096.f), h2f(hv.y) + h2f(lv.y) * (1.f/4096.f),
                   h2f(hv.z) + h2f(lv.z) * (1.f/4096.f), h2f(hv.w) + h2f(lv.w) * (1.f/4096.f) };
  float gga[4] = { gg.x, gg.y, gg.z, gg.w };
  float bba[4] = { bb.x, bb.y, bb.z, bb.w };
  ushort ho[4], lo[4];
  #pragma unroll
  for (int e = 0; e < 4; ++e) {
    float nv = (vin[e] - m) * rs * gga[e] + bba[e];
    nv = nv >= 0.f ? nv : 0.02f * nv;
    half_t hh = (half_t)nv;
    ho[e] = f2h(nv);
    lo[e] = f2h((nv - (float)hh) * 4096.f);
  }
  *(ushort4*)(h + off) = make_ushort4(ho[0], ho[1], ho[2], ho[3]);
  *(ushort4*)(l + off) = make_ushort4(lo[0], lo[1], lo[2], lo[3]);
}

// GN + GLU: Dh [t][1024] h-only -> dqa [t][640] cols [0,512)
__global__ __launch_bounds__(256) void gn_glu_k(
    const half_t* __restrict__ Dh, half_t* __restrict__ dqa,
    const float* __restrict__ g, const float* __restrict__ bt,
    const float* __restrict__ part, int P, float invN) {
  const int b = blockIdx.y, tid = threadIdx.x;
  float s = 0.f, ss = 0.f;
  if (tid < P) { s = part[((size_t)b * MAXP + tid) * 2]; ss = part[((size_t)b * MAXP + tid) * 2 + 1]; }
  for (int off = 32; off; off >>= 1) { s += __shfl_down(s, off); ss += __shfl_down(ss, off); }
  __shared__ float l1[4], l2[4], smv[2];
  if ((tid & 63) == 0) { l1[tid >> 6] = s; l2[tid >> 6] = ss; }
  __syncthreads();
  if (tid == 0) {
    float S = l1[0] + l1[1] + l1[2] + l1[3], SS = l2[0] + l2[1] + l2[2] + l2[3];
    float m = S * invN;
    float var = fmaxf(SS * invN - m * m, 0.f);
    smv[0] = m; smv[1] = 1.f / sqrtf(var + 1e-5f);
  }
  __syncthreads();
  const float m = smv[0], rs = smv[1];
  size_t i0 = ((size_t)blockIdx.x * 256 + tid) * 4;   // over T*512
  const int t = (int)(i0 >> 9), c = (int)(i0 & 511);
  size_t ib = (size_t)b * T_LEN * 1024 + (size_t)t * 1024 + c;
  ushort4 av = *(ushort4*)(Dh + ib);
  ushort4 gv = *(ushort4*)(Dh + ib + 512);
  float4 g1 = *(const float4*)(g + c), b1 = *(const float4*)(bt + c);
  float4 g2 = *(const float4*)(g + 512 + c), b2 = *(const float4*)(bt + 512 + c);
  float aa[4] = { h2f(av.x), h2f(av.y), h2f(av.z), h2f(av.w) };
  float gt[4] = { h2f(gv.x), h2f(gv.y), h2f(gv.z), h2f(gv.w) };
  float g1a[4] = { g1.x, g1.y, g1.z, g1.w }, b1a[4] = { b1.x, b1.y, b1.z, b1.w };
  float g2a[4] = { g2.x, g2.y, g2.z, g2.w }, b2a[4] = { b2.x, b2.y, b2.z, b2.w };
  ushort ov[4];
  #pragma unroll
  for (int e = 0; e < 4; ++e) {
    float na = (aa[e] - m) * rs * g1a[e] + b1a[e];
    float ng = (gt[e] - m) * rs * g2a[e] + b2a[e];
    ov[e] = f2h(na * (1.f / (1.f + expf(-ng))));
  }
  *(ushort4*)(dqa + (size_t)b * T_LEN * 640 + (size_t)t * 640 + c) = make_ushort4(ov[0], ov[1], ov[2], ov[3]);
}

// fused argmax(512) + write dq1 [t][256] = [zq | yv]; one wave per t
__global__ __launch_bounds__(256) void argzq_k(
    const float* __restrict__ sims, const int* __restrict__ y,
    const float* __restrict__ cbn, const float* __restrict__ sn,
    half_t* __restrict__ dq1) {
  const int b = blockIdx.y;
  const int wv = threadIdx.x >> 6, lane = threadIdx.x & 63;
  const int t = blockIdx.x * 4 + wv;
  const float* srow = sims + ((size_t)b * T_LEN + t) * 512;
  float best = -3.4e38f; int bi = 0;
  #pragma unroll
  for (int j = 0; j < 8; ++j) {
    int k = lane * 8 + j;
    float v = srow[k];
    if (v > best) { best = v; bi = k; }
  }
  #pragma unroll
  for (int off = 1; off < 64; off <<= 1) {
    float ob = __shfl_xor(best, off);
    int oi = __shfl_xor(bi, off);
    if (ob > best || (ob == best && oi < bi)) { best = ob; bi = oi; }
  }
  const int yy = y[(size_t)b * T_LEN + t];
  const int c = lane * 4;
  float4 v = (c < 128) ? *(const float4*)(cbn + (size_t)bi * 128 + c)
                       : *(const float4*)(sn + (size_t)yy * 128 + (c - 128));
  *(ushort4*)(dq1 + ((size_t)b * T_LEN + t) * 256 + c) =
      make_ushort4(f2h(v.x), f2h(v.y), f2h(v.z), f2h(v.w));
}

// fill dqa [t][640] cols [512,640) with yv (persists across both GLU stages)
__global__ void yv_dqa_k(const int* __restrict__ y, const float* __restrict__ sn,
                         half_t* __restrict__ dqa) {
  const int b = blockIdx.y;
  size_t i0 = ((size_t)blockIdx.x * 256 + threadIdx.x) * 4;   // over T*128
  const int t = (int)(i0 >> 7), c = (int)(i0 & 127);
  const int yy = y[(size_t)b * T_LEN + t];
  float4 v = *(const float4*)(sn + (size_t)yy * 128 + c);
  *(ushort4*)(dqa + (size_t)b * T_LEN * 640 + (size_t)t * 640 + 512 + c) =
      make_ushort4(f2h(v.x), f2h(v.y), f2h(v.z), f2h(v.w));
}

// ======================= host side =======================

extern "C" void kernel_launch(void* const* d_in, const int* in_sizes, int n_in,
                              void* d_out, int out_size, void* d_ws, size_t ws_size,
                              hipStream_t stream) {
  const int T = T_LEN;
  const float* x   = (const float*)d_in[0];
  const int*   y   = (const int*)d_in[1];
  const float* spk = (const float*)d_in[2];
  const float* cb  = (const float*)d_in[3];
  const float* ew0 = (const float*)d_in[4];
  const float* eb0 = (const float*)d_in[5];
  const float* eg0 = (const float*)d_in[6];
  const float* et0 = (const float*)d_in[7];
  const float* ew1 = (const float*)d_in[8];
  const float* eb1 = (const float*)d_in[9];
  const float* eg1 = (const float*)d_in[10];
  const float* et1 = (const float*)d_in[11];
  const float* ew2 = (const float*)d_in[12];
  const float* eb2 = (const float*)d_in[13];
  const float* eg2 = (const float*)d_in[14];
  const float* et2 = (const float*)d_in[15];
  const float* mw  = (const float*)d_in[16];
  const float* mb  = (const float*)d_in[17];
  const float* dw0 = (const float*)d_in[18];
  const float* db0 = (const float*)d_in[19];
  const float* dg0 = (const float*)d_in[20];
  const float* dt0 = (const float*)d_in[21];
  const float* dw1 = (const float*)d_in[22];
  const float* db1 = (const float*)d_in[23];
  const float* dg1 = (const float*)d_in[24];
  const float* dt1 = (const float*)d_in[25];
  const float* dw2 = (const float*)d_in[26];
  const float* db2 = (const float*)d_in[27];
  float* out = (float*)d_out;
  (void)in_sizes; (void)n_in; (void)out_size;

  // weight plane elems ([o][tap][i], padded)
  const size_t PW_E0 = (size_t)1024 * 5 * 64;
  const size_t PW_E1 = (size_t)512 * 5 * 1024;
  const size_t PW_E2 = (size_t)512 * 5 * 512;
  const size_t PW_VQ = (size_t)512 * 1 * 512;
  const size_t PW_D0 = (size_t)1024 * 5 * 256;
  const size_t PW_D1 = (size_t)1024 * 5 * 640;
  const size_t PW_D2 = (size_t)64 * 5 * 640;

  auto al = [](size_t bytes) { return (bytes + 255) & ~(size_t)255; };
  const size_t fixedB = al(512 * 128 * 4) + al(64 * 128 * 4) + al((size_t)16 * MAXP * 2 * 4) +
                        al(512 * 4) + al((size_t)512 * 512 * 4);
  const size_t wfullB = 2 * al(PW_E0 * 2) + 2 * al(PW_E1 * 2) + 2 * al(PW_E2 * 2) +
                        2 * al(PW_VQ * 2) + al(PW_D0 * 2) + al(PW_D1 * 2) + al(PW_D2 * 2);
  const size_t wshB = 2 * al(PW_E1 * 2);   // largest layer (pair)
  auto chunkB = [&](int c) {
    return 2 * al((size_t)c * T * 64 * 2) +        // xpair
           al((size_t)c * T * 1024 * 2 * 2) +      // poolA (pair 1024)
           al((size_t)c * T * 512 * 2 * 2) +       // poolB
           al((size_t)c * T * 512 * 2 * 2);        // poolC
  };

  int bc = 0; bool shw = false;
  {
    const int cands[5] = {16, 8, 4, 2, 1};
    for (int i = 0; i < 5 && !bc; ++i)
      if (fixedB + wfullB + chunkB(cands[i]) <= ws_size) bc = cands[i];
    if (!bc) {
      shw = true;
      for (int i = 0; i < 5 && !bc; ++i)
        if (fixedB + wshB + chunkB(cands[i]) <= ws_size) bc = cands[i];
    }
    if (!bc) return;
  }

  char* base = (char*)d_ws;
  size_t off = 0;
  auto takeB = [&](size_t bytes) -> char* { char* r = base + off; off += al(bytes); return r; };

  float* cbn  = (float*)takeB(512 * 128 * 4);
  float* sn   = (float*)takeB(64 * 128 * 4);
  float* part = (float*)takeB((size_t)16 * MAXP * 2 * 4);
  float* vqb  = (float*)takeB(512 * 4);
  float* Wf   = (float*)takeB((size_t)512 * 512 * 4);

  half_t *we0h, *we0l, *we1h, *we1l, *we2h, *we2l, *wvqh, *wvql, *wd0h, *wd1h, *wd2h;
  if (!shw) {
    we0h = (half_t*)takeB(PW_E0 * 2); we0l = (half_t*)takeB(PW_E0 * 2);
    we1h = (half_t*)takeB(PW_E1 * 2); we1l = (half_t*)takeB(PW_E1 * 2);
    we2h = (half_t*)takeB(PW_E2 * 2); we2l = (half_t*)takeB(PW_E2 * 2);
    wvqh = (half_t*)takeB(PW_VQ * 2); wvql = (half_t*)takeB(PW_VQ * 2);
    wd0h = (half_t*)takeB(PW_D0 * 2);
    wd1h = (half_t*)takeB(PW_D1 * 2);
    wd2h = (half_t*)takeB(PW_D2 * 2);
  } else {
    half_t* slab = (half_t*)takeB(2 * al(PW_E1 * 2));
    we0h = slab; we0l = slab + PW_E0;
    we1h = slab; we1l = slab + PW_E1;
    we2h = slab; we2l = slab + PW_E2;
    wvqh = slab; wvql = slab + PW_VQ;
    wd0h = slab; wd1h = slab; wd2h = slab;
  }
  half_t* xh = (half_t*)takeB((size_t)bc * T * 64 * 2);
  half_t* xl = (half_t*)takeB((size_t)bc * T * 64 * 2);
  const size_t APL = (size_t)bc * T * 1024;
  const size_t BPL = (size_t)bc * T * 512;
  half_t* pA = (half_t*)takeB(APL * 2 * 2);
  half_t* pB = (half_t*)takeB(BPL * 2 * 2);
  half_t* pC = (half_t*)takeB(BPL * 2 * 2);
  // aliases (per-plane arrays, natural per-sample strides)
  half_t *Y1h = pA, *Y1l = pA + APL, *D1h = pA, *dq1 = pA + APL;
  half_t *Y2h = pB, *Y2l = pB + BPL; float* sims = (float*)pB;
  half_t *Y3h = pC, *Y3l = pC + BPL, *dqa = pC;

  dim3 blk(256);
  auto nblk = [](size_t total) { return dim3((unsigned)((total + 255) / 256)); };
  auto prepW = [&](const float* src, half_t* h, half_t* l, int Ci, int Co, int K,
                   int Cip, int Cop, int mode) {
    prep_w_split_k<<<nblk((size_t)Cop * K * Cip), blk, 0, stream>>>(src, h, l, Ci, Co, K, Cip, Cop, mode);
  };

  // ---- one-time prep ----
  norm_rows_k<<<576, 128, 0, stream>>>(cb, spk, cbn, sn);
  compose_vq_k<<<1024, blk, 0, stream>>>(cbn, mw, Wf);
  compose_vqb_k<<<2, blk, 0, stream>>>(cbn, mb, vqb);
  if (!shw) {
    prepW(ew0, we0h, we0l, 39, 1024, 5, 64, 1024, 0);
    prepW(ew1, we1h, we1l, 1024, 512, 5, 1024, 512, 0);
    prepW(ew2, we2h, we2l, 512, 512, 5, 512, 512, 0);
    prepW(Wf,  wvqh, wvql, 512, 512, 1, 512, 512, 0);
    prepW(dw0, wd0h, nullptr, 256, 1024, 5, 256, 1024, 1);
    prepW(dw1, wd1h, nullptr, 640, 1024, 5, 640, 1024, 1);
    prepW(dw2, wd2h, nullptr, 640, 39, 5, 640, 64, 1);
  }

  const float inv1024 = 1.f / (1024.f * T), inv512 = 1.f / (512.f * T);

  for (int b0 = 0; b0 < 16; b0 += bc) {
    const int* yc = y + (size_t)b0 * T;
    float* outc = out + (size_t)b0 * 39 * T;

    xsplit_k<<<nblk((size_t)bc * 64 * T), blk, 0, stream>>>(x + (size_t)b0 * 39 * T, xh, xl, bc);

    // encoder 0: 64(39) -> 1024
    if (shw) prepW(ew0, we0h, we0l, 39, 1024, 5, 64, 1024, 0);
    conv_mfma<1, 5, 128, 0><<<dim3(16, 16, bc), blk, 0, stream>>>(
        xh, xl, we0h, we0l, eb0, Y1h, Y1l, nullptr, part, 64, 1024, 1024);
    gn_lrelu_pair_k<<<dim3(2048, bc), blk, 0, stream>>>(Y1h, Y1l, eg0, et0, part, 1024, 256, inv1024);

    // encoder 1: 1024 -> 512
    if (shw) prepW(ew1, we1h, we1l, 1024, 512, 5, 1024, 512, 0);
    conv_mfma<1, 5, 128, 0><<<dim3(16, 8, bc), blk, 0, stream>>>(
        Y1h, Y1l, we1h, we1l, eb1, Y2h, Y2l, nullptr, part, 1024, 512, 512);
    gn_lrelu_pair_k<<<dim3(1024, bc), blk, 0, stream>>>(Y2h, Y2l, eg1, et1, part, 512, 128, inv512);

    // encoder 2: 512 -> 512
    if (shw) prepW(ew2, we2h, we2l, 512, 512, 5, 512, 512, 0);
    conv_mfma<1, 5, 128, 0><<<dim3(16, 8, bc), blk, 0, stream>>>(
        Y2h, Y2l, we2h, we2l, eb2, Y3h, Y3l, nullptr, part, 512, 512, 512);
    gn_lrelu_pair_k<<<dim3(1024, bc), blk, 0, stream>>>(Y3h, Y3l, eg2, et2, part, 512, 128, inv512);

    // fused bottleneck+VQ: sims = (cbn.Wm) h3 + cbn.mb   (512 -> 512, fp32 out)
    if (shw) prepW(Wf, wvqh, wvql, 512, 512, 1, 512, 512, 0);
    conv_mfma<1, 1, 128, 1><<<dim3(16, 8, bc), blk, 0, stream>>>(
        Y3h, Y3l, wvqh, wvql, vqb, nullptr, nullptr, sims, nullptr, 512, 512, 512);

    // argmax + concat(zq, yv) -> dq1 [t][256]
    argzq_k<<<dim3(512, bc), blk, 0, stream>>>(sims, yc, cbn, sn, dq1);
    // fill dqa yv region [512,640) once (persists across both GLU stages)
    yv_dqa_k<<<dim3(256, bc), blk, 0, stream>>>(yc, sn, dqa);

    // decoder 0: 256 -> 1024 (h-only + stats), GN+GLU -> dqa[0,512)
    if (shw) prepW(dw0, wd0h, nullptr, 256, 1024, 5, 256, 1024, 1);
    conv_mfma<0, 5, 128, 3><<<dim3(16, 16, bc), blk, 0, stream>>>(
        dq1, nullptr, wd0h, nullptr, db0, D1h, nullptr, nullptr, part, 256, 1024, 1024);
    gn_glu_k<<<dim3(1024, bc), blk, 0, stream>>>(D1h, dqa, dg0, dt0, part, 256, inv1024);

    // decoder 1: 640 -> 1024, GN+GLU -> dqa[0,512)
    if (shw) prepW(dw1, wd1h, nullptr, 640, 1024, 5, 640, 1024, 1);
    conv_mfma<0, 5, 128, 3><<<dim3(16, 16, bc), blk, 0, stream>>>(
        dqa, nullptr, wd1h, nullptr, db1, D1h, nullptr, nullptr, part, 640, 1024, 1024);
    gn_glu_k<<<dim3(1024, bc), blk, 0, stream>>>(D1h, dqa, dg1, dt1, part, 256, inv1024);

    // decoder 2: 640 -> 39, fp32 [c][t] to d_out
    if (shw) prepW(dw2, wd2h, nullptr, 640, 39, 5, 640, 64, 1);
    conv_mfma<0, 5, 64, 2><<<dim3(32, 1, bc), blk, 0, stream>>>(
        dqa, nullptr, wd2h, nullptr, db2, nullptr, nullptr, outc, nullptr, 640, 39, 0);
  }
}